// Round 2
// baseline (17320.407 us; speedup 1.0000x reference)
//
#include <hip/hip_runtime.h>
#include <cmath>

// ---------------------------------------------------------------------------
// 2-layer LSTM, T=256 B=64 D=H=1024. fp16 MFMA (fp32 accum).
//
// Phase 1: pack W/X into MFMA fragment layouts (packed gate col p = h*4+g).
// Phase 2: per layer: big parallel xGEMM (Zx = x@Wx + b), then ONE persistent
//          cooperative kernel runs all timesteps of the recurrence with a
//          device-scope flag barrier between steps.
//
//  A-pack (M x K):  AP[mt][kt][lane][j] = A[mt*16 + (lane&15)][kt*32 + (lane>>4)*8 + j]
//  B-pack (K x G):  WP[nt][kt][lane][j] = W[kt*32 + (lane>>4)*8 + j][origcol(nt*16 + (lane&15))]
//  MFMA 16x16x32 f16: D[row=(lane>>4)*4+r][col=lane&15]
// ---------------------------------------------------------------------------

typedef _Float16 half8 __attribute__((ext_vector_type(8)));
typedef float f32x4 __attribute__((ext_vector_type(4)));

constexpr int Tt = 256, Bb = 64, Kd = 1024, Gg = 4096;
constexpr int KT = 32;                               // k-tiles (K=1024/32)
constexpr size_t MT_ELEMS = (size_t)KT * 64 * 8;     // 16384 elems per m-tile
constexpr size_t HSTEP = 4 * MT_ELEMS;               // A-pack elems per timestep

__device__ __forceinline__ f32x4 zero4() { f32x4 z = {0.f, 0.f, 0.f, 0.f}; return z; }
__device__ __forceinline__ float fast_sig(float x) { return 1.f / (1.f + __expf(-x)); }
__device__ __forceinline__ float fast_tanh(float x) {
    x = fminf(15.f, fmaxf(-15.f, x));
    float e = __expf(2.f * x);
    return (e - 1.f) / (e + 1.f);
}

// ---- pack W: fp32 [2048][4096] -> 4 fp16 B-packed halves -------------------
__global__ void pack_w_kernel(const float* __restrict__ W0, const float* __restrict__ W1,
                              _Float16* __restrict__ WP0x, _Float16* __restrict__ WP0h,
                              _Float16* __restrict__ WP1x, _Float16* __restrict__ WP1h) {
    int idx = blockIdx.x * 256 + threadIdx.x;      // [0, 256*32*64)
    int half_id = blockIdx.y;                      // 0:W0x 1:W0h 2:W1x 3:W1h
    const float* src = (half_id < 2) ? W0 : W1;
    int rowoff = (half_id & 1) * 1024;
    _Float16* dst = (half_id == 0) ? WP0x : (half_id == 1) ? WP0h : (half_id == 2) ? WP1x : WP1h;

    int lane = idx & 63;
    int kt = (idx >> 6) & 31;
    int nt = idx >> 11;
    int p = nt * 16 + (lane & 15);
    int col = (p & 3) * 1024 + (p >> 2);
    int kbase = rowoff + kt * 32 + (lane >> 4) * 8;
    half8 v;
#pragma unroll
    for (int j = 0; j < 8; ++j) v[j] = (_Float16)src[(size_t)(kbase + j) * Gg + col];
    *reinterpret_cast<half8*>(dst + (size_t)idx * 8) = v;
}

__global__ void pack_bias_kernel(const float* __restrict__ b0, const float* __restrict__ b1,
                                 float* __restrict__ bp0, float* __restrict__ bp1) {
    int idx = blockIdx.x * 256 + threadIdx.x;      // [0, 8192)
    int l = idx >> 12, p = idx & 4095;
    int col = (p & 3) * 1024 + (p >> 2);
    (l ? bp1 : bp0)[p] = (l ? b1 : b0)[col];
}

// ---- pack X: fp32 [16384][1024] -> fp16 A-pack -----------------------------
__global__ void pack_a_kernel(const float* __restrict__ X, _Float16* __restrict__ XP) {
    int idx = blockIdx.x * 256 + threadIdx.x;      // [0, 1024*32*64)
    int lane = idx & 63;
    int kt = (idx >> 6) & 31;
    int mt = idx >> 11;
    int m = mt * 16 + (lane & 15);
    int kbase = kt * 32 + (lane >> 4) * 8;
    const float* srow = X + (size_t)m * Kd + kbase;
    half8 v;
#pragma unroll
    for (int j = 0; j < 8; ++j) v[j] = (_Float16)srow[j];
    *reinterpret_cast<half8*>(XP + (size_t)idx * 8) = v;
}

// ---- big x-part GEMM: Z[m][p] = AP@WP + bias. LDS-free (packed operands). --
__global__ __launch_bounds__(256) void xgemm_kernel(const _Float16* __restrict__ AP,
                                                    const _Float16* __restrict__ WP,
                                                    const float* __restrict__ bias,
                                                    float* __restrict__ Z) {
    int lane = threadIdx.x & 63, wave = threadIdx.x >> 6;
    int wrow = wave >> 1, wcol = wave & 1;
    int mtb = blockIdx.x * 8 + wrow * 4;
    int ntb = blockIdx.y * 8 + wcol * 4;

    f32x4 acc[4][4];
#pragma unroll
    for (int i = 0; i < 4; ++i)
#pragma unroll
        for (int j = 0; j < 4; ++j) acc[i][j] = zero4();

    for (int kt = 0; kt < KT; ++kt) {
        half8 a[4], b[4];
#pragma unroll
        for (int i = 0; i < 4; ++i)
            a[i] = *reinterpret_cast<const half8*>(AP + (((size_t)(mtb + i) * KT + kt) * 64 + lane) * 8);
#pragma unroll
        for (int j = 0; j < 4; ++j)
            b[j] = *reinterpret_cast<const half8*>(WP + (((size_t)(ntb + j) * KT + kt) * 64 + lane) * 8);
#pragma unroll
        for (int i = 0; i < 4; ++i)
#pragma unroll
            for (int j = 0; j < 4; ++j)
                acc[i][j] = __builtin_amdgcn_mfma_f32_16x16x32_f16(a[i], b[j], acc[i][j], 0, 0, 0);
    }

    int r0 = (lane >> 4) * 4, cc = lane & 15;
#pragma unroll
    for (int j = 0; j < 4; ++j) {
        int p = (ntb + j) * 16 + cc;
        float bs = bias[p];
#pragma unroll
        for (int i = 0; i < 4; ++i) {
            int mbase = (mtb + i) * 16 + r0;
#pragma unroll
            for (int r = 0; r < 4; ++r)
                Z[(size_t)(mbase + r) * Gg + p] = acc[i][j][r] + bs;
        }
    }
}

// ---- persistent recurrent kernel: all Tc steps in one launch ---------------
// grid 256 (wg = nt, 16 packed cols = 4 h-cols), block 256 = 4 waves (wave =
// 16-batch m-tile). Wh slice lives in registers; c lives in registers.
// Step barrier: flags[t][wg] with release-store / relaxed-spin + fences.
__global__ __launch_bounds__(256, 1) void lstm_persist_kernel(
    const float* __restrict__ Z,           // [Tc][64][4096] chunk of Zx
    int t0, int Tc,
    const _Float16* __restrict__ WPh,      // B-pack of recurrent weights
    const _Float16* __restrict__ hfirst,   // A-pack h for step t0
    _Float16* __restrict__ HP,             // A-pack h sequence (written per step)
    float* __restrict__ cbuf,              // c carry between chunks
    float* __restrict__ outF,              // optional fp32 [T][64][1024] output
    unsigned* __restrict__ flags)          // [256 steps][256 wgs]
{
    int lane = threadIdx.x & 63, w = threadIdx.x >> 6;
    int nt = blockIdx.x;

    // recurrent-weight slice for this wg: 32 frags x 16B/lane = 128 VGPRs
    half8 bf[KT];
#pragma unroll
    for (int kt = 0; kt < KT; ++kt)
        bf[kt] = *reinterpret_cast<const half8*>(WPh + (((size_t)nt * KT + kt) * 64 + lane) * 8);

    int q = lane >> 4, cc = lane & 15;     // MFMA C-layout coords
    int bl = lane >> 2, hl = lane & 3;     // gate-phase coords
    int b = w * 16 + bl;
    int hcol = nt * 4 + hl;
    size_t cidx = (size_t)b * 1024 + hcol;
    float creg = (t0 == 0) ? 0.f : cbuf[cidx];
    // h A-pack output index for this thread (m=b in m-tile w, k=hcol)
    size_t hoidx = (((size_t)w * KT + (hcol >> 5)) * 64 + ((hcol >> 3) & 3) * 16 + bl) * 8 + (hcol & 7);

    __shared__ float zs[4][16][17];

    for (int t = t0; t < t0 + Tc; ++t) {
        // prefetch Zx (independent of the step barrier)
        const float* zp = Z + (((size_t)(t - t0) * 64 + w * 16 + q * 4) * Gg) + nt * 16 + cc;
        float z0 = zp[0], z1 = zp[Gg], z2 = zp[2 * (size_t)Gg], z3 = zp[3 * (size_t)Gg];

        const _Float16* hp = (t == t0) ? hfirst : (HP + (size_t)(t - 1) * HSTEP);

        if (t > t0) {
            unsigned* fl = flags + (size_t)(t - 1) * 256 + threadIdx.x;
            while (__hip_atomic_load(fl, __ATOMIC_RELAXED, __HIP_MEMORY_SCOPE_AGENT) == 0) {}
        }
        __syncthreads();
        if (t > t0) __threadfence();       // acquire: make producers' h visible

        // z_h = hprev @ Wh : 32 MFMAs, 4 independent acc chains
        f32x4 a0 = zero4(), a1 = zero4(), a2 = zero4(), a3 = zero4();
#pragma unroll
        for (int kt = 0; kt < KT; kt += 4) {
            half8 h0 = *reinterpret_cast<const half8*>(hp + (((size_t)w * KT + kt + 0) * 64 + lane) * 8);
            half8 h1 = *reinterpret_cast<const half8*>(hp + (((size_t)w * KT + kt + 1) * 64 + lane) * 8);
            half8 h2 = *reinterpret_cast<const half8*>(hp + (((size_t)w * KT + kt + 2) * 64 + lane) * 8);
            half8 h3 = *reinterpret_cast<const half8*>(hp + (((size_t)w * KT + kt + 3) * 64 + lane) * 8);
            a0 = __builtin_amdgcn_mfma_f32_16x16x32_f16(h0, bf[kt + 0], a0, 0, 0, 0);
            a1 = __builtin_amdgcn_mfma_f32_16x16x32_f16(h1, bf[kt + 1], a1, 0, 0, 0);
            a2 = __builtin_amdgcn_mfma_f32_16x16x32_f16(h2, bf[kt + 2], a2, 0, 0, 0);
            a3 = __builtin_amdgcn_mfma_f32_16x16x32_f16(h3, bf[kt + 3], a3, 0, 0, 0);
        }
        f32x4 acc = (a0 + a1) + (a2 + a3);

        zs[w][q * 4 + 0][cc] = acc[0] + z0;
        zs[w][q * 4 + 1][cc] = acc[1] + z1;
        zs[w][q * 4 + 2][cc] = acc[2] + z2;
        zs[w][q * 4 + 3][cc] = acc[3] + z3;
        __syncthreads();

        float zi = zs[w][bl][hl * 4 + 0];
        float zj = zs[w][bl][hl * 4 + 1];
        float zf = zs[w][bl][hl * 4 + 2];
        float zo = zs[w][bl][hl * 4 + 3];
        float cn = creg * fast_sig(zf + 1.0f) + fast_sig(zi) * fast_tanh(zj);
        float hn = fast_tanh(cn) * fast_sig(zo);
        creg = cn;

        HP[(size_t)t * HSTEP + hoidx] = (_Float16)hn;
        if (outF) outF[(size_t)t * (Bb * 1024) + cidx] = hn;

        __syncthreads();                   // all 4 waves' h stores drained
        if (threadIdx.x == 0) {
            __threadfence();               // publish h at agent scope
            __hip_atomic_store(flags + (size_t)t * 256 + nt, 1u,
                               __ATOMIC_RELEASE, __HIP_MEMORY_SCOPE_AGENT);
        }
    }
    cbuf[cidx] = creg;                     // carry c to next chunk
}

// ---------------------------------------------------------------------------
extern "C" void kernel_launch(void* const* d_in, const int* in_sizes, int n_in,
                              void* d_out, int out_size, void* d_ws, size_t ws_size,
                              hipStream_t stream) {
    const float* X  = (const float*)d_in[0];
    const float* W0 = (const float*)d_in[1];
    const float* b0 = (const float*)d_in[2];
    const float* W1 = (const float*)d_in[3];
    const float* b1 = (const float*)d_in[4];
    float* out = (float*)d_out;

    char* ws = (char*)d_ws;
    size_t off = 0;
    auto take = [&](size_t n) -> void* {
        void* r = ws + off;
        off += (n + 255) & ~(size_t)255;
        return r;
    };

    const size_t WPB = (size_t)Kd * Gg * 2;            // 8 MiB per packed W half
    _Float16* WP0x = (_Float16*)take(WPB);
    _Float16* WP0h = (_Float16*)take(WPB);
    _Float16* WP1x = (_Float16*)take(WPB);
    _Float16* WP1h = (_Float16*)take(WPB);
    float* bp0 = (float*)take(Gg * 4);
    float* bp1 = (float*)take(Gg * 4);
    const size_t APB = (size_t)Tt * Bb * Kd * 2;       // 32 MiB
    _Float16* XP  = (_Float16*)take(APB);
    _Float16* H1P = (_Float16*)take(APB);
    _Float16* H2P = (_Float16*)take(APB);
    _Float16* hzero = (_Float16*)take((size_t)Bb * 1024 * 2);
    float* c0 = (float*)take((size_t)Bb * 1024 * 4);
    float* c1 = (float*)take((size_t)Bb * 1024 * 4);
    unsigned* flags0 = (unsigned*)take((size_t)Tt * 256 * 4);   // 256 KiB
    unsigned* flags1 = (unsigned*)take((size_t)Tt * 256 * 4);

    int Tc = 256;   // Z-chunk timesteps, shrink to fit workspace
    while (Tc > 8 && off + (size_t)Tc * Bb * Gg * 4 > ws_size) Tc >>= 1;
    float* Z = (float*)take((size_t)Tc * Bb * Gg * 4);

    hipMemsetAsync(hzero, 0, (size_t)Bb * 1024 * 2, stream);
    hipMemsetAsync(flags0, 0, (size_t)Tt * 256 * 4, stream);
    hipMemsetAsync(flags1, 0, (size_t)Tt * 256 * 4, stream);

    pack_w_kernel<<<dim3(2048, 4), 256, 0, stream>>>(W0, W1, WP0x, WP0h, WP1x, WP1h);
    pack_bias_kernel<<<32, 256, 0, stream>>>(b0, b1, bp0, bp1);
    pack_a_kernel<<<8192, 256, 0, stream>>>(X, XP);

    auto coop = [&](const float* Zc, int t0v, int Tcv, const _Float16* WPh,
                    const _Float16* hfirst, _Float16* HP, float* cbuf,
                    float* outF, unsigned* flags) {
        void* args[] = {(void*)&Zc, (void*)&t0v, (void*)&Tcv, (void*)&WPh, (void*)&hfirst,
                        (void*)&HP, (void*)&cbuf, (void*)&outF, (void*)&flags};
        hipLaunchCooperativeKernel(reinterpret_cast<void*>(lstm_persist_kernel),
                                   dim3(256), dim3(256), args, 0, stream);
    };

    // ---- layer 0 ----
    for (int t0 = 0; t0 < Tt; t0 += Tc) {
        xgemm_kernel<<<dim3(Tc * Bb / 128, Gg / 128), 256, 0, stream>>>(
            XP + (size_t)t0 * HSTEP, WP0x, bp0, Z);
        const _Float16* hf = (t0 == 0) ? hzero : H1P + (size_t)(t0 - 1) * HSTEP;
        coop(Z, t0, Tc, WP0h, hf, H1P, c0, nullptr, flags0);
    }
    // ---- layer 1 ----
    for (int t0 = 0; t0 < Tt; t0 += Tc) {
        xgemm_kernel<<<dim3(Tc * Bb / 128, Gg / 128), 256, 0, stream>>>(
            H1P + (size_t)t0 * HSTEP, WP1x, bp1, Z);
        const _Float16* hf = (t0 == 0) ? hzero : H2P + (size_t)(t0 - 1) * HSTEP;
        coop(Z, t0, Tc, WP1h, hf, H2P, c1, out, flags1);
    }
    (void)in_sizes; (void)n_in; (void)out_size;
}

// Round 3
// 5072.102 us; speedup vs baseline: 3.4148x; 3.4148x over previous
//
#include <hip/hip_runtime.h>
#include <cmath>

// ---------------------------------------------------------------------------
// 2-layer LSTM, T=256 B=64 D=H=1024. fp16 MFMA (fp32 accum).
//
// Phase 1: pack W/X into MFMA fragment layouts (packed gate col p = h*4+g).
// Phase 2: per layer: big parallel xGEMM (Zx = x@Wx + b, fp16, nt-major), then
//          ONE persistent cooperative kernel runs all 256 timesteps with a
//          padded version-flag barrier between steps (no cache-invalidating
//          fences: h is published via agent-scope write-through atomic stores
//          and read at virgin addresses).
//
//  A-pack (M x K):  AP[mt][kt][lane][j] = A[mt*16 + (lane&15)][kt*32 + (lane>>4)*8 + j]
//  B-pack (K x G):  WP[nt][kt][lane][j] = W[kt*32 + (lane>>4)*8 + j][origcol(nt*16 + (lane&15))]
//  MFMA 16x16x32 f16: D[row=(lane>>4)*4+r][col=lane&15]
// ---------------------------------------------------------------------------

typedef _Float16 half8 __attribute__((ext_vector_type(8)));
typedef float f32x4 __attribute__((ext_vector_type(4)));

constexpr int Tt = 256, Bb = 64, Kd = 1024, Gg = 4096;
constexpr int KT = 32;                               // k-tiles (K=1024/32)
constexpr size_t MT_ELEMS = (size_t)KT * 64 * 8;     // 16384 elems per m-tile
constexpr size_t HSTEP = 4 * MT_ELEMS;               // A-pack elems per timestep
constexpr int FLAG_STRIDE = 32;                      // uints: 128B per flag

__device__ __forceinline__ f32x4 zero4() { f32x4 z = {0.f, 0.f, 0.f, 0.f}; return z; }
__device__ __forceinline__ float fast_sig(float x) { return 1.f / (1.f + __expf(-x)); }
__device__ __forceinline__ float fast_tanh(float x) {
    x = fminf(15.f, fmaxf(-15.f, x));
    float e = __expf(2.f * x);
    return (e - 1.f) / (e + 1.f);
}

// ---- pack W: fp32 [2048][4096] -> 4 fp16 B-packed halves -------------------
__global__ void pack_w_kernel(const float* __restrict__ W0, const float* __restrict__ W1,
                              _Float16* __restrict__ WP0x, _Float16* __restrict__ WP0h,
                              _Float16* __restrict__ WP1x, _Float16* __restrict__ WP1h) {
    int idx = blockIdx.x * 256 + threadIdx.x;      // [0, 256*32*64)
    int half_id = blockIdx.y;                      // 0:W0x 1:W0h 2:W1x 3:W1h
    const float* src = (half_id < 2) ? W0 : W1;
    int rowoff = (half_id & 1) * 1024;
    _Float16* dst = (half_id == 0) ? WP0x : (half_id == 1) ? WP0h : (half_id == 2) ? WP1x : WP1h;

    int lane = idx & 63;
    int kt = (idx >> 6) & 31;
    int nt = idx >> 11;
    int p = nt * 16 + (lane & 15);
    int col = (p & 3) * 1024 + (p >> 2);
    int kbase = rowoff + kt * 32 + (lane >> 4) * 8;
    half8 v;
#pragma unroll
    for (int j = 0; j < 8; ++j) v[j] = (_Float16)src[(size_t)(kbase + j) * Gg + col];
    *reinterpret_cast<half8*>(dst + (size_t)idx * 8) = v;
}

__global__ void pack_bias_kernel(const float* __restrict__ b0, const float* __restrict__ b1,
                                 float* __restrict__ bp0, float* __restrict__ bp1) {
    int idx = blockIdx.x * 256 + threadIdx.x;      // [0, 8192)
    int l = idx >> 12, p = idx & 4095;
    int col = (p & 3) * 1024 + (p >> 2);
    (l ? bp1 : bp0)[p] = (l ? b1 : b0)[col];
}

// ---- pack X: fp32 [16384][1024] -> fp16 A-pack -----------------------------
__global__ void pack_a_kernel(const float* __restrict__ X, _Float16* __restrict__ XP) {
    int idx = blockIdx.x * 256 + threadIdx.x;      // [0, 1024*32*64)
    int lane = idx & 63;
    int kt = (idx >> 6) & 31;
    int mt = idx >> 11;
    int m = mt * 16 + (lane & 15);
    int kbase = kt * 32 + (lane >> 4) * 8;
    const float* srow = X + (size_t)m * Kd + kbase;
    half8 v;
#pragma unroll
    for (int j = 0; j < 8; ++j) v[j] = (_Float16)srow[j];
    *reinterpret_cast<half8*>(XP + (size_t)idx * 8) = v;
}

// ---- big x-part GEMM: Z'[t][nt][64][16] fp16 = AP@WP + bias ----------------
__global__ __launch_bounds__(256) void xgemm_kernel(const _Float16* __restrict__ AP,
                                                    const _Float16* __restrict__ WP,
                                                    const float* __restrict__ bias,
                                                    _Float16* __restrict__ Z) {
    int lane = threadIdx.x & 63, wave = threadIdx.x >> 6;
    int wrow = wave >> 1, wcol = wave & 1;
    int mtb = blockIdx.x * 8 + wrow * 4;
    int ntb = blockIdx.y * 8 + wcol * 4;

    f32x4 acc[4][4];
#pragma unroll
    for (int i = 0; i < 4; ++i)
#pragma unroll
        for (int j = 0; j < 4; ++j) acc[i][j] = zero4();

    for (int kt = 0; kt < KT; ++kt) {
        half8 a[4], b[4];
#pragma unroll
        for (int i = 0; i < 4; ++i)
            a[i] = *reinterpret_cast<const half8*>(AP + (((size_t)(mtb + i) * KT + kt) * 64 + lane) * 8);
#pragma unroll
        for (int j = 0; j < 4; ++j)
            b[j] = *reinterpret_cast<const half8*>(WP + (((size_t)(ntb + j) * KT + kt) * 64 + lane) * 8);
#pragma unroll
        for (int i = 0; i < 4; ++i)
#pragma unroll
            for (int j = 0; j < 4; ++j)
                acc[i][j] = __builtin_amdgcn_mfma_f32_16x16x32_f16(a[i], b[j], acc[i][j], 0, 0, 0);
    }

    int r0 = (lane >> 4) * 4, cc = lane & 15;
#pragma unroll
    for (int j = 0; j < 4; ++j) {
        int p_tile = ntb + j;
        float bs = bias[p_tile * 16 + cc];
#pragma unroll
        for (int i = 0; i < 4; ++i) {
#pragma unroll
            for (int r = 0; r < 4; ++r) {
                int m = (mtb + i) * 16 + r0 + r;         // t_rel*64 + batch
                Z[(((size_t)(m >> 6) * 256 + p_tile) * 64 + (m & 63)) * 16 + cc] =
                    (_Float16)(acc[i][j][r] + bs);
            }
        }
    }
}

// ---- persistent recurrent kernel: Tc steps in one cooperative launch -------
// grid 256 (wg = nt : 16 packed cols = 4 h-cols), block 256 = 4 waves (wave =
// 16-batch m-tile). Step barrier: padded version flags, release-store /
// relaxed-spin; h published via agent-scope write-through stores, consumed via
// plain loads at virgin addresses (no invalidating fences).
__global__ __launch_bounds__(256, 1) void lstm_persist_kernel(
    const _Float16* __restrict__ Z,        // [Tc][256][64][16] fp16 Zx chunk
    int t0, int Tc,
    const _Float16* __restrict__ WPh,      // B-pack of recurrent weights
    const _Float16* __restrict__ hfirst,   // A-pack h for step t0
    _Float16* __restrict__ HP,             // A-pack h sequence (per step)
    float* __restrict__ cbuf,              // c carry between chunks
    float* __restrict__ outF,              // optional fp32 [T][64][1024] output
    unsigned* __restrict__ flags)          // [256 wgs] padded version counters
{
    int lane = threadIdx.x & 63, w = threadIdx.x >> 6;
    int nt = blockIdx.x;

    // recurrent-weight slice for this wg: 32 frags x 16B/lane = 128 VGPRs
    half8 bf[KT];
#pragma unroll
    for (int kt = 0; kt < KT; ++kt)
        bf[kt] = *reinterpret_cast<const half8*>(WPh + (((size_t)nt * KT + kt) * 64 + lane) * 8);

    int q = lane >> 4, cc = lane & 15;     // MFMA C-layout coords
    int bl = lane >> 2, hl = lane & 3;     // gate-phase coords
    int b = w * 16 + bl;
    int hcol = nt * 4 + hl;
    size_t cidx = (size_t)b * 1024 + hcol;
    float creg = (t0 == 0) ? 0.f : cbuf[cidx];
    size_t hoidx = (((size_t)w * KT + (hcol >> 5)) * 64 + ((hcol >> 3) & 3) * 16 + bl) * 8 + (hcol & 7);

    __shared__ float zs[4][16][17];

    unsigned* myflag = flags + (size_t)threadIdx.x * FLAG_STRIDE;  // spin target: wg #threadIdx.x

    for (int t = t0; t < t0 + Tc; ++t) {
        // prefetch Zx (contiguous 2KB per wg; independent of the step barrier)
        const _Float16* zp = Z + (((size_t)(t - t0) * 256 + nt) * 64 + w * 16 + q * 4) * 16 + cc;
        float z0 = (float)zp[0], z1 = (float)zp[16], z2 = (float)zp[32], z3 = (float)zp[48];

        const _Float16* hp = (t == t0) ? hfirst : (HP + (size_t)(t - 1) * HSTEP);

        if (t > t0) {
            // wait until wg #threadIdx.x has published step t-1 (version t)
            while (__hip_atomic_load(myflag, __ATOMIC_RELAXED, __HIP_MEMORY_SCOPE_AGENT) < (unsigned)t)
                __builtin_amdgcn_s_sleep(1);
        }
        __syncthreads();
        asm volatile("" ::: "memory");     // no h loads hoisted above the spin

        // z_h = hprev @ Wh : 32 MFMAs, 4 independent acc chains
        f32x4 a0 = zero4(), a1 = zero4(), a2 = zero4(), a3 = zero4();
#pragma unroll
        for (int kt = 0; kt < KT; kt += 4) {
            half8 h0 = *reinterpret_cast<const half8*>(hp + (((size_t)w * KT + kt + 0) * 64 + lane) * 8);
            half8 h1 = *reinterpret_cast<const half8*>(hp + (((size_t)w * KT + kt + 1) * 64 + lane) * 8);
            half8 h2 = *reinterpret_cast<const half8*>(hp + (((size_t)w * KT + kt + 2) * 64 + lane) * 8);
            half8 h3 = *reinterpret_cast<const half8*>(hp + (((size_t)w * KT + kt + 3) * 64 + lane) * 8);
            a0 = __builtin_amdgcn_mfma_f32_16x16x32_f16(h0, bf[kt + 0], a0, 0, 0, 0);
            a1 = __builtin_amdgcn_mfma_f32_16x16x32_f16(h1, bf[kt + 1], a1, 0, 0, 0);
            a2 = __builtin_amdgcn_mfma_f32_16x16x32_f16(h2, bf[kt + 2], a2, 0, 0, 0);
            a3 = __builtin_amdgcn_mfma_f32_16x16x32_f16(h3, bf[kt + 3], a3, 0, 0, 0);
        }
        f32x4 acc = (a0 + a1) + (a2 + a3);

        zs[w][q * 4 + 0][cc] = acc[0] + z0;
        zs[w][q * 4 + 1][cc] = acc[1] + z1;
        zs[w][q * 4 + 2][cc] = acc[2] + z2;
        zs[w][q * 4 + 3][cc] = acc[3] + z3;
        __syncthreads();

        float zi = zs[w][bl][hl * 4 + 0];
        float zj = zs[w][bl][hl * 4 + 1];
        float zf = zs[w][bl][hl * 4 + 2];
        float zo = zs[w][bl][hl * 4 + 3];
        float cn = creg * fast_sig(zf + 1.0f) + fast_sig(zi) * fast_tanh(zj);
        float hn = fast_tanh(cn) * fast_sig(zo);
        creg = cn;

        // publish h (and out) write-through at agent scope: local L2 stays clean
        _Float16 hh = (_Float16)hn;
        unsigned short hbits;
        __builtin_memcpy(&hbits, &hh, 2);
        __hip_atomic_store((unsigned short*)(HP + (size_t)t * HSTEP + hoidx), hbits,
                           __ATOMIC_RELAXED, __HIP_MEMORY_SCOPE_AGENT);
        if (outF)
            __hip_atomic_store(outF + (size_t)t * (Bb * 1024) + cidx, hn,
                               __ATOMIC_RELAXED, __HIP_MEMORY_SCOPE_AGENT);

        __syncthreads();                   // per-wave vmcnt(0) drain: h stores complete
        if (threadIdx.x == 0)
            __hip_atomic_store(flags + (size_t)nt * FLAG_STRIDE, (unsigned)(t + 1),
                               __ATOMIC_RELEASE, __HIP_MEMORY_SCOPE_AGENT);
    }
    cbuf[cidx] = creg;                     // carry c to next chunk (plain; kernel boundary)
}

// ---------------------------------------------------------------------------
extern "C" void kernel_launch(void* const* d_in, const int* in_sizes, int n_in,
                              void* d_out, int out_size, void* d_ws, size_t ws_size,
                              hipStream_t stream) {
    const float* X  = (const float*)d_in[0];
    const float* W0 = (const float*)d_in[1];
    const float* b0 = (const float*)d_in[2];
    const float* W1 = (const float*)d_in[3];
    const float* b1 = (const float*)d_in[4];
    float* out = (float*)d_out;

    char* ws = (char*)d_ws;
    size_t off = 0;
    auto take = [&](size_t n) -> void* {
        void* r = ws + off;
        off += (n + 255) & ~(size_t)255;
        return r;
    };

    const size_t WPB = (size_t)Kd * Gg * 2;            // 8 MiB per packed W half
    _Float16* WP0x = (_Float16*)take(WPB);
    _Float16* WP0h = (_Float16*)take(WPB);
    _Float16* WP1x = (_Float16*)take(WPB);
    _Float16* WP1h = (_Float16*)take(WPB);
    float* bp0 = (float*)take(Gg * 4);
    float* bp1 = (float*)take(Gg * 4);
    const size_t APB = (size_t)Tt * Bb * Kd * 2;       // 32 MiB
    _Float16* XP  = (_Float16*)take(APB);
    _Float16* H1P = (_Float16*)take(APB);
    _Float16* H2P = XP;   // layer-1 h pack aliases XP (XP dead after layer 0)
    _Float16* hzero = (_Float16*)take((size_t)Bb * 1024 * 2);
    float* c0 = (float*)take((size_t)Bb * 1024 * 4);
    float* c1 = (float*)take((size_t)Bb * 1024 * 4);
    unsigned* flags0 = (unsigned*)take((size_t)256 * FLAG_STRIDE * 4);  // 32 KiB
    unsigned* flags1 = (unsigned*)take((size_t)256 * FLAG_STRIDE * 4);

    int Tc = 256;   // Z-chunk timesteps (fp16 Z), shrink to fit workspace
    while (Tc > 8 && off + (size_t)Tc * Bb * Gg * 2 > ws_size) Tc >>= 1;
    _Float16* Z = (_Float16*)take((size_t)Tc * Bb * Gg * 2);

    hipMemsetAsync(hzero, 0, (size_t)Bb * 1024 * 2, stream);
    hipMemsetAsync(flags0, 0, (size_t)256 * FLAG_STRIDE * 4, stream);
    hipMemsetAsync(flags1, 0, (size_t)256 * FLAG_STRIDE * 4, stream);

    pack_w_kernel<<<dim3(2048, 4), 256, 0, stream>>>(W0, W1, WP0x, WP0h, WP1x, WP1h);
    pack_bias_kernel<<<32, 256, 0, stream>>>(b0, b1, bp0, bp1);
    pack_a_kernel<<<8192, 256, 0, stream>>>(X, XP);

    auto coop = [&](const _Float16* Zc, int t0v, int Tcv, const _Float16* WPh,
                    const _Float16* hfirst, _Float16* HP, float* cbuf,
                    float* outF, unsigned* flags) {
        void* args[] = {(void*)&Zc, (void*)&t0v, (void*)&Tcv, (void*)&WPh, (void*)&hfirst,
                        (void*)&HP, (void*)&cbuf, (void*)&outF, (void*)&flags};
        hipLaunchCooperativeKernel(reinterpret_cast<void*>(lstm_persist_kernel),
                                   dim3(256), dim3(256), args, 0, stream);
    };

    // ---- layer 0 ----
    for (int t0 = 0; t0 < Tt; t0 += Tc) {
        xgemm_kernel<<<dim3(Tc * Bb / 128, Gg / 128), 256, 0, stream>>>(
            XP + (size_t)t0 * HSTEP, WP0x, bp0, Z);
        const _Float16* hf = (t0 == 0) ? hzero : H1P + (size_t)(t0 - 1) * HSTEP;
        coop(Z, t0, Tc, WP0h, hf, H1P, c0, nullptr, flags0);
    }
    // ---- layer 1 ----
    for (int t0 = 0; t0 < Tt; t0 += Tc) {
        xgemm_kernel<<<dim3(Tc * Bb / 128, Gg / 128), 256, 0, stream>>>(
            H1P + (size_t)t0 * HSTEP, WP1x, bp1, Z);
        const _Float16* hf = (t0 == 0) ? hzero : H2P + (size_t)(t0 - 1) * HSTEP;
        coop(Z, t0, Tc, WP1h, hf, H2P, c1, out, flags1);
    }
    (void)in_sizes; (void)n_in; (void)out_size;
}